// Round 1
// baseline (2636.175 us; speedup 1.0000x reference)
//
#include <hip/hip_runtime.h>

// Problem constants (from setup_inputs): B=4, C=64, H=256, W=448, fp32.
#define BB 4
#define CC 64
#define HH 256
#define WW 448
constexpr int HW = HH * WW;          // 114688
constexpr int CHW = CC * HW;         // 7340032

// ---------------------------------------------------------------------------
// Kernel 1: forward bilinear splat (scatter-add with HW fp32 atomics).
// One thread per source pixel; inner loop over the 64 channels.
// acc  = d_out  [B, C, H, W]  (value channels, pre-zeroed)
// wacc = d_ws   [B, H, W]     (weight channel, pre-zeroed)
// ---------------------------------------------------------------------------
__global__ __launch_bounds__(256) void splat_kernel(
    const float* __restrict__ inp,   // [B, C, H, W]
    const float* __restrict__ flow,  // [B, 2, H, W] (dx, dy)
    const float* __restrict__ mask,  // [B, 1, H, W]
    float* __restrict__ acc,         // [B, C, H, W]
    float* __restrict__ wacc)        // [B, H, W]
{
    int p = blockIdx.x * 256 + threadIdx.x;
    if (p >= BB * HW) return;
    int b   = p / HW;
    int rem = p - b * HW;
    int y   = rem / WW;
    int x   = rem - y * WW;

    float dx = flow[(b * 2 + 0) * HW + rem];
    float dy = flow[(b * 2 + 1) * HW + rem];
    float tx = (float)x + dx;
    float ty = (float)y + dy;
    float x0f = floorf(tx), y0f = floorf(ty);
    int   x0  = (int)x0f,   y0  = (int)y0f;
    float wx1 = tx - x0f, wx0 = 1.0f - wx1;
    float wy1 = ty - y0f, wy0 = 1.0f - wy1;

    float m = expf(mask[b * HW + rem]);

    // 4 corners: j = (ybit<<1)|xbit
    int   xs[2]  = {x0, x0 + 1};
    int   ys[2]  = {y0, y0 + 1};
    float wxs[2] = {wx0, wx1};
    float wys[2] = {wy0, wy1};

    int   cidx[4];
    float cw[4];
    bool  cv[4];
#pragma unroll
    for (int j = 0; j < 4; ++j) {
        int   xi = xs[j & 1];
        int   yi = ys[j >> 1];
        bool  valid = (xi >= 0) & (xi < WW) & (yi >= 0) & (yi < HH);
        cidx[j] = yi * WW + xi;
        cw[j]   = wxs[j & 1] * wys[j >> 1];
        cv[j]   = valid;
    }

    // weight channel (the appended "m" channel)
    float* wbase = wacc + b * HW;
#pragma unroll
    for (int j = 0; j < 4; ++j) {
        if (cv[j]) unsafeAtomicAdd(wbase + cidx[j], cw[j] * m);
    }

    // value channels
    const float* ibase = inp + b * CHW + rem;
    float*       obase = acc + b * CHW;
    for (int c = 0; c < CC; ++c) {
        float v = ibase[c * HW] * m;
#pragma unroll
        for (int j = 0; j < 4; ++j) {
            if (cv[j]) unsafeAtomicAdd(obase + c * HW + cidx[j], cw[j] * v);
        }
    }
}

// ---------------------------------------------------------------------------
// Kernel 2: in-place normalize  out = out / (w + 1e-7), float4-vectorized.
// ---------------------------------------------------------------------------
__global__ __launch_bounds__(256) void norm_kernel(
    float* __restrict__ out,          // [B, C, H, W]
    const float* __restrict__ wacc)   // [B, H, W]
{
    int i = blockIdx.x * 256 + threadIdx.x;        // float4 index
    constexpr int N4 = BB * CHW / 4;               // 7340032
    if (i >= N4) return;
    int e   = i * 4;                               // element index (fits int32)
    int b   = e / CHW;
    int pix = e % HW;                              // HW divisible by 4 -> same channel row

    float4 a = *reinterpret_cast<const float4*>(out + e);
    float4 w = *reinterpret_cast<const float4*>(wacc + b * HW + pix);
    float4 r;
    r.x = a.x / (w.x + 1e-7f);
    r.y = a.y / (w.y + 1e-7f);
    r.z = a.z / (w.z + 1e-7f);
    r.w = a.w / (w.w + 1e-7f);
    *reinterpret_cast<float4*>(out + e) = r;
}

extern "C" void kernel_launch(void* const* d_in, const int* in_sizes, int n_in,
                              void* d_out, int out_size, void* d_ws, size_t ws_size,
                              hipStream_t stream) {
    const float* inp  = (const float*)d_in[0];  // tenInput  [4,64,256,448]
    const float* flow = (const float*)d_in[1];  // tenFlow   [4,2,256,448]
    const float* mask = (const float*)d_in[2];  // importance_mask [4,1,256,448]
    float* out  = (float*)d_out;
    float* wacc = (float*)d_ws;                 // weight channel accumulator [4,256,448]

    // Zero accumulators every call (harness poisons once; graph replays reuse).
    hipMemsetAsync(out,  0, (size_t)BB * CHW * sizeof(float), stream);
    hipMemsetAsync(wacc, 0, (size_t)BB * HW  * sizeof(float), stream);

    int npix = BB * HW;
    splat_kernel<<<(npix + 255) / 256, 256, 0, stream>>>(inp, flow, mask, out, wacc);

    constexpr int N4 = BB * CHW / 4;
    norm_kernel<<<(N4 + 255) / 256, 256, 0, stream>>>(out, wacc);
}

// Round 2
// 722.984 us; speedup vs baseline: 3.6462x; 3.6462x over previous
//
#include <hip/hip_runtime.h>

// Problem constants: B=4, C=64, H=256, W=448, fp32.
#define BB 4
#define CC 64
#define HH 256
#define WW 448
constexpr int HW  = HH * WW;    // 114688
constexpr int CHW = CC * HW;    // 7340032

// Gather-tile geometry
#define TX 32                   // tile width  (W=448 -> 14 tiles)
#define TY 16                   // tile height (H=256 -> 16 tiles)
#define TH 7                    // source window halo; "local" iff |d| <= 6
#define LOCAL_MAX 6.0f
#define WINX (TX + 2*TH)        // 46
#define WINY (TY + 2*TH)        // 30
#define NSRC (WINX * WINY)      // 1380
#define MAXS 6                  // ceil(NSRC / 256)
#define NCH 16                  // channels per LDS chunk
#define NCHUNK (CC / NCH)       // 4
#define TPB 256

// ws layout (floats): [0, B*HW) = weight accumulator (outliers only);
//                     [B*HW]    = outlier flag (as u32)

// ---------------------------------------------------------------------------
// K1: detect any source pixel with |flow| > LOCAL_MAX (rare path trigger).
// ---------------------------------------------------------------------------
__global__ __launch_bounds__(TPB) void flag_kernel(
    const float* __restrict__ flow, unsigned* __restrict__ flag)
{
    int p = blockIdx.x * TPB + threadIdx.x;
    if (p >= BB * HW) return;
    int b = p / HW, rem = p - b * HW;
    float dx = flow[(b * 2 + 0) * HW + rem];
    float dy = flow[(b * 2 + 1) * HW + rem];
    if (!((fabsf(dx) <= LOCAL_MAX) && (fabsf(dy) <= LOCAL_MAX)))
        atomicOr(flag, 1u);
}

// ---------------------------------------------------------------------------
// K2: zero d_out only if outliers exist (they atomically accumulate into it).
// ---------------------------------------------------------------------------
__global__ __launch_bounds__(TPB) void cond_zero_kernel(
    float4* __restrict__ out4, const unsigned* __restrict__ flag)
{
    if (*flag == 0u) return;
    const int n4 = BB * CHW / 4;
    for (int i = blockIdx.x * TPB + threadIdx.x; i < n4; i += gridDim.x * TPB)
        out4[i] = float4{0.f, 0.f, 0.f, 0.f};
}

// ---------------------------------------------------------------------------
// K3: rare-path scatter for outlier sources (global atomics, ~0 pixels usually).
// ---------------------------------------------------------------------------
__global__ __launch_bounds__(TPB) void outlier_kernel(
    const float* __restrict__ inp, const float* __restrict__ flow,
    const float* __restrict__ mask, float* __restrict__ acc,
    float* __restrict__ wacc, const unsigned* __restrict__ flag)
{
    if (*flag == 0u) return;
    int p = blockIdx.x * TPB + threadIdx.x;
    if (p >= BB * HW) return;
    int b = p / HW, rem = p - b * HW;
    int y = rem / WW, x = rem - y * WW;

    float dx = flow[(b * 2 + 0) * HW + rem];
    float dy = flow[(b * 2 + 1) * HW + rem];
    if ((fabsf(dx) <= LOCAL_MAX) && (fabsf(dy) <= LOCAL_MAX)) return; // local: gather handles

    float tx = (float)x + dx, ty = (float)y + dy;
    float x0f = floorf(tx), y0f = floorf(ty);
    int   x0 = (int)x0f, y0 = (int)y0f;
    float fx = tx - x0f, fy = ty - y0f;
    float wx[2] = {1.0f - fx, fx};
    float wy[2] = {1.0f - fy, fy};
    float m = expf(mask[b * HW + rem]);

    int   cidx[4];
    float cw[4];
    bool  cv[4];
#pragma unroll
    for (int j = 0; j < 4; ++j) {
        int xi = x0 + (j & 1), yi = y0 + (j >> 1);
        cv[j]   = (xi >= 0) & (xi < WW) & (yi >= 0) & (yi < HH);
        cidx[j] = yi * WW + xi;
        cw[j]   = wx[j & 1] * wy[j >> 1] * m;
    }
    float* wbase = wacc + b * HW;
#pragma unroll
    for (int j = 0; j < 4; ++j)
        if (cv[j]) unsafeAtomicAdd(wbase + cidx[j], cw[j]);
    const float* ibase = inp + b * CHW + rem;
    float*       obase = acc + b * CHW;
    for (int c = 0; c < CC; ++c) {
        float v = ibase[c * HW];
#pragma unroll
        for (int j = 0; j < 4; ++j)
            if (cv[j]) unsafeAtomicAdd(obase + c * HW + cidx[j], cw[j] * v);
    }
}

// ---------------------------------------------------------------------------
// K4: main gather-splat. Block owns exclusive TXxTY output tile; scans the
// (TX+2*TH)x(TY+2*TH) source window, scatter-adds into LDS, fuses normalize,
// writes with plain coalesced stores.
// ---------------------------------------------------------------------------
__global__ __launch_bounds__(TPB) void gather_kernel(
    const float* __restrict__ inp, const float* __restrict__ flow,
    const float* __restrict__ mask, float* __restrict__ out,
    const float* __restrict__ wacc, const unsigned* __restrict__ flag)
{
    __shared__ float wlds[TX * TY];
    __shared__ float vlds[NCH][TX * TY];

    const int b   = blockIdx.z;
    const int bx0 = blockIdx.x * TX;
    const int by0 = blockIdx.y * TY;
    const int tid = threadIdx.x;

    for (int i = tid; i < TX * TY; i += TPB) wlds[i] = 0.0f;
    __syncthreads();

    // --- weight pass: compute per-source corner data, cache in registers,
    //     accumulate the weight plane in LDS.
    int   spix[MAXS], lxs[MAXS], lys[MAXS];
    float wgt[MAXS][4];

#pragma unroll
    for (int k = 0; k < MAXS; ++k) {
        const int s  = tid + k * TPB;
        const int sy = s / WINX;
        const int sx = s - sy * WINX;
        const int gx = bx0 - TH + sx;
        const int gy = by0 - TH + sy;
        bool v = (s < NSRC) & (gx >= 0) & (gx < WW) & (gy >= 0) & (gy < HH);
        const int sp = gy * WW + gx;
        float dx = 0.f, dy = 0.f, m = 0.f;
        if (v) {
            dx = flow[(b * 2 + 0) * HW + sp];
            dy = flow[(b * 2 + 1) * HW + sp];
            v  = (fabsf(dx) <= LOCAL_MAX) && (fabsf(dy) <= LOCAL_MAX);
        }
        if (v) m = expf(mask[b * HW + sp]);

        const float tx  = (float)gx + dx;
        const float ty  = (float)gy + dy;
        const float x0f = floorf(tx), y0f = floorf(ty);
        const float fx  = tx - x0f,  fy  = ty - y0f;
        const float ox  = 1.0f - fx, oy  = 1.0f - fy;
        int lx = (int)x0f - bx0;
        int ly = (int)y0f - by0;
        if (!v) { lx = -100; ly = -100; }

        spix[k] = sp; lxs[k] = lx; lys[k] = ly;
        wgt[k][0] = ox * oy * m;
        wgt[k][1] = fx * oy * m;
        wgt[k][2] = ox * fy * m;
        wgt[k][3] = fx * fy * m;

#pragma unroll
        for (int j = 0; j < 4; ++j) {
            const int cx = lx + (j & 1), cy = ly + (j >> 1);
            if (cx >= 0 && cx < TX && cy >= 0 && cy < TY)
                atomicAdd(&wlds[cy * TX + cx], wgt[k][j]);
        }
    }
    __syncthreads();

    // --- per-pixel reciprocal denominators (2 pixels per thread)
    const bool has_out = (*flag != 0u);
    float rden[2];
    int   gpix[2];
#pragma unroll
    for (int t = 0; t < 2; ++t) {
        const int p  = tid + t * TPB;
        const int py = p / TX, px = p - py * TX;
        gpix[t] = (by0 + py) * WW + (bx0 + px);
        rden[t] = 1.0f / (wlds[p] + wacc[b * HW + gpix[t]] + 1e-7f);
    }

    // --- channel chunks
    for (int cc = 0; cc < NCHUNK; ++cc) {
        float4* vz = (float4*)&vlds[0][0];
        for (int i = tid; i < NCH * TX * TY / 4; i += TPB)
            vz[i] = float4{0.f, 0.f, 0.f, 0.f};
        __syncthreads();

        const float* __restrict__ ib = inp + (b * CC + cc * NCH) * HW;
#pragma unroll
        for (int k = 0; k < MAXS; ++k) {
            const int lx = lxs[k], ly = lys[k];
            // skip sources whose 2x2 corner box misses this tile entirely
            if (lx >= -1 && lx < TX && ly >= -1 && ly < TY) {
                float v[NCH];
#pragma unroll
                for (int c = 0; c < NCH; ++c) v[c] = ib[c * HW + spix[k]];
#pragma unroll
                for (int j = 0; j < 4; ++j) {
                    const int cx = lx + (j & 1), cy = ly + (j >> 1);
                    if (cx >= 0 && cx < TX && cy >= 0 && cy < TY) {
                        const float wj = wgt[k][j];
                        const int   li = cy * TX + cx;
#pragma unroll
                        for (int c = 0; c < NCH; ++c)
                            atomicAdd(&vlds[c][li], wj * v[c]);
                    }
                }
            }
        }
        __syncthreads();

        const int obase = (b * CC + cc * NCH) * HW;
#pragma unroll
        for (int t = 0; t < 2; ++t) {
            const int p = tid + t * TPB;
#pragma unroll
            for (int c = 0; c < NCH; ++c) {
                float a = vlds[c][p];
                const int gi = obase + c * HW + gpix[t];
                if (has_out) a += out[gi];   // outlier contributions (rare)
                out[gi] = a * rden[t];
            }
        }
        __syncthreads();
    }
}

extern "C" void kernel_launch(void* const* d_in, const int* in_sizes, int n_in,
                              void* d_out, int out_size, void* d_ws, size_t ws_size,
                              hipStream_t stream) {
    const float* inp  = (const float*)d_in[0];  // [4,64,256,448]
    const float* flow = (const float*)d_in[1];  // [4,2,256,448]
    const float* mask = (const float*)d_in[2];  // [4,1,256,448]
    float*    out  = (float*)d_out;
    float*    wacc = (float*)d_ws;                          // [B,HW] outlier weights
    unsigned* flag = (unsigned*)((float*)d_ws + BB * HW);   // outlier flag

    // zero wacc + flag every call (deterministic under graph replay)
    hipMemsetAsync(d_ws, 0, (size_t)(BB * HW + 4) * sizeof(float), stream);

    const int npix = BB * HW;
    flag_kernel<<<(npix + TPB - 1) / TPB, TPB, 0, stream>>>(flow, flag);
    cond_zero_kernel<<<2048, TPB, 0, stream>>>((float4*)out, flag);
    outlier_kernel<<<(npix + TPB - 1) / TPB, TPB, 0, stream>>>(inp, flow, mask, out, wacc, flag);
    gather_kernel<<<dim3(WW / TX, HH / TY, BB), TPB, 0, stream>>>(inp, flow, mask, out, wacc, flag);
}

// Round 3
// 692.984 us; speedup vs baseline: 3.8041x; 1.0433x over previous
//
#include <hip/hip_runtime.h>

// Problem constants: B=4, C=64, H=256, W=448, fp32.
#define BB 4
#define CC 64
#define HH 256
#define WW 448
constexpr int HW  = HH * WW;    // 114688
constexpr int CHW = CC * HW;    // 7340032

// Gather-tile geometry
#define TX 32                   // tile width  (W=448 -> 14 tiles)
#define TY 16                   // tile height (H=256 -> 16 tiles)
#define TH 7                    // source window halo; "local" iff |d| <= 6
#define LOCAL_MAX 6.0f
#define WINX (TX + 2*TH)        // 46
#define WINY (TY + 2*TH)        // 30
#define NSRC (WINX * WINY)      // 1380
#define MAXS 6                  // ceil(NSRC / 256)
#define NCH 8                   // channels per block (chunk-group)
#define NGRP (CC / NCH)         // 8 chunk-groups
#define TPB 256
#define TXTY (TX * TY)          // 512

// ws layout (floats): [0, B*HW) = weight accumulator (outliers only);
//                     [B*HW]    = outlier flag (as u32)

// ---------------------------------------------------------------------------
// K1: detect any source pixel with |flow| > LOCAL_MAX (rare path trigger).
// ---------------------------------------------------------------------------
__global__ __launch_bounds__(TPB) void flag_kernel(
    const float* __restrict__ flow, unsigned* __restrict__ flag)
{
    int p = blockIdx.x * TPB + threadIdx.x;
    if (p >= BB * HW) return;
    int b = p / HW, rem = p - b * HW;
    float dx = flow[(b * 2 + 0) * HW + rem];
    float dy = flow[(b * 2 + 1) * HW + rem];
    if (!((fabsf(dx) <= LOCAL_MAX) && (fabsf(dy) <= LOCAL_MAX)))
        atomicOr(flag, 1u);
}

// ---------------------------------------------------------------------------
// K2: zero d_out only if outliers exist (they atomically accumulate into it).
// ---------------------------------------------------------------------------
__global__ __launch_bounds__(TPB) void cond_zero_kernel(
    float4* __restrict__ out4, const unsigned* __restrict__ flag)
{
    if (*flag == 0u) return;
    const int n4 = BB * CHW / 4;
    for (int i = blockIdx.x * TPB + threadIdx.x; i < n4; i += gridDim.x * TPB)
        out4[i] = float4{0.f, 0.f, 0.f, 0.f};
}

// ---------------------------------------------------------------------------
// K3: rare-path scatter for outlier sources (global atomics, ~0 pixels usually).
// ---------------------------------------------------------------------------
__global__ __launch_bounds__(TPB) void outlier_kernel(
    const float* __restrict__ inp, const float* __restrict__ flow,
    const float* __restrict__ mask, float* __restrict__ acc,
    float* __restrict__ wacc, const unsigned* __restrict__ flag)
{
    if (*flag == 0u) return;
    int p = blockIdx.x * TPB + threadIdx.x;
    if (p >= BB * HW) return;
    int b = p / HW, rem = p - b * HW;
    int y = rem / WW, x = rem - y * WW;

    float dx = flow[(b * 2 + 0) * HW + rem];
    float dy = flow[(b * 2 + 1) * HW + rem];
    if ((fabsf(dx) <= LOCAL_MAX) && (fabsf(dy) <= LOCAL_MAX)) return; // local: gather handles

    float tx = (float)x + dx, ty = (float)y + dy;
    float x0f = floorf(tx), y0f = floorf(ty);
    int   x0 = (int)x0f, y0 = (int)y0f;
    float fx = tx - x0f, fy = ty - y0f;
    float wx[2] = {1.0f - fx, fx};
    float wy[2] = {1.0f - fy, fy};
    float m = expf(mask[b * HW + rem]);

    int   cidx[4];
    float cw[4];
    bool  cv[4];
#pragma unroll
    for (int j = 0; j < 4; ++j) {
        int xi = x0 + (j & 1), yi = y0 + (j >> 1);
        cv[j]   = (xi >= 0) & (xi < WW) & (yi >= 0) & (yi < HH);
        cidx[j] = yi * WW + xi;
        cw[j]   = wx[j & 1] * wy[j >> 1] * m;
    }
    float* wbase = wacc + b * HW;
#pragma unroll
    for (int j = 0; j < 4; ++j)
        if (cv[j]) unsafeAtomicAdd(wbase + cidx[j], cw[j]);
    const float* ibase = inp + b * CHW + rem;
    float*       obase = acc + b * CHW;
    for (int c = 0; c < CC; ++c) {
        float v = ibase[c * HW];
#pragma unroll
        for (int j = 0; j < 4; ++j)
            if (cv[j]) unsafeAtomicAdd(obase + c * HW + cidx[j], cw[j] * v);
    }
}

// ---------------------------------------------------------------------------
// K4: main gather-splat. Block owns an exclusive TXxTY output tile AND an
// 8-channel group. Single merged pass over the source window accumulates the
// weight plane + 8 value planes in LDS; then normalize + coalesced stores.
// 18 KB LDS -> 8 blocks/CU; grid 7168 blocks -> deep pipelining.
// ---------------------------------------------------------------------------
__global__ __launch_bounds__(TPB, 8) void gather_kernel(
    const float* __restrict__ inp, const float* __restrict__ flow,
    const float* __restrict__ mask, float* __restrict__ out,
    const float* __restrict__ wacc, const unsigned* __restrict__ flag)
{
    __shared__ float lds[(1 + NCH) * TXTY];   // [0,TXTY) = weights, then NCH planes
    float* wlds = lds;

    const int b    = blockIdx.z >> 3;         // batch
    const int grp  = blockIdx.z & 7;          // channel group
    const int bx0  = blockIdx.x * TX;
    const int by0  = blockIdx.y * TY;
    const int tid  = threadIdx.x;

    // zero all LDS planes
    {
        float4* z = (float4*)lds;
        constexpr int n4 = (1 + NCH) * TXTY / 4;   // 1152
#pragma unroll
        for (int i = 0; i < (n4 + TPB - 1) / TPB; ++i) {
            int idx = tid + i * TPB;
            if (idx < n4) z[idx] = float4{0.f, 0.f, 0.f, 0.f};
        }
    }
    __syncthreads();

    const float* __restrict__ fxp = flow + (b * 2 + 0) * HW;
    const float* __restrict__ fyp = flow + (b * 2 + 1) * HW;
    const float* __restrict__ mp  = mask + b * HW;
    const float* __restrict__ ib  = inp + (b * CC + grp * NCH) * HW;

    // --- merged accumulation pass over the source window
#pragma unroll 2
    for (int k = 0; k < MAXS; ++k) {
        const int s  = tid + k * TPB;
        const int sy = s / WINX;
        const int sx = s - sy * WINX;
        const int gx = bx0 - TH + sx;
        const int gy = by0 - TH + sy;
        bool v = (s < NSRC) & (gx >= 0) & (gx < WW) & (gy >= 0) & (gy < HH);
        if (!v) continue;
        const int sp = gy * WW + gx;

        const float dx = fxp[sp];
        const float dy = fyp[sp];
        if (!((fabsf(dx) <= LOCAL_MAX) && (fabsf(dy) <= LOCAL_MAX))) continue;

        const float tx  = (float)gx + dx;
        const float ty  = (float)gy + dy;
        const float x0f = floorf(tx), y0f = floorf(ty);
        const int   lx  = (int)x0f - bx0;
        const int   ly  = (int)y0f - by0;
        // 2x2 corner box vs tile: skip if no overlap at all
        if (lx < -1 || lx >= TX || ly < -1 || ly >= TY) continue;

        const float fx = tx - x0f, fy = ty - y0f;
        const float ox = 1.0f - fx, oy = 1.0f - fy;
        const float m  = expf(mp[sp]);
        float w4[4] = {ox * oy * m, fx * oy * m, ox * fy * m, fx * fy * m};

        // weight plane
#pragma unroll
        for (int j = 0; j < 4; ++j) {
            const int cx = lx + (j & 1), cy = ly + (j >> 1);
            if (cx >= 0 && cx < TX && cy >= 0 && cy < TY)
                atomicAdd(&wlds[cy * TX + cx], w4[j]);
        }
        // value planes (8 channels)
        float vv[NCH];
#pragma unroll
        for (int c = 0; c < NCH; ++c) vv[c] = ib[c * HW + sp];
#pragma unroll
        for (int j = 0; j < 4; ++j) {
            const int cx = lx + (j & 1), cy = ly + (j >> 1);
            if (cx >= 0 && cx < TX && cy >= 0 && cy < TY) {
                const float wj = w4[j];
                float* vp = &lds[TXTY + cy * TX + cx];
#pragma unroll
                for (int c = 0; c < NCH; ++c)
                    atomicAdd(vp + c * TXTY, wj * vv[c]);
            }
        }
    }
    __syncthreads();

    // --- normalize + store (2 pixels per thread x 8 channels)
    const bool has_out = (*flag != 0u);
    const int  obase   = (b * CC + grp * NCH) * HW;
#pragma unroll
    for (int t = 0; t < 2; ++t) {
        const int p  = tid + t * TPB;
        const int py = p >> 5, px = p & 31;           // TX = 32
        const int gpix = (by0 + py) * WW + (bx0 + px);
        const float rden = 1.0f / (wlds[p] + wacc[b * HW + gpix] + 1e-7f);
#pragma unroll
        for (int c = 0; c < NCH; ++c) {
            float a = lds[TXTY + c * TXTY + p];
            const int gi = obase + c * HW + gpix;
            if (has_out) a += out[gi];                 // rare outlier contributions
            out[gi] = a * rden;
        }
    }
}

extern "C" void kernel_launch(void* const* d_in, const int* in_sizes, int n_in,
                              void* d_out, int out_size, void* d_ws, size_t ws_size,
                              hipStream_t stream) {
    const float* inp  = (const float*)d_in[0];  // [4,64,256,448]
    const float* flow = (const float*)d_in[1];  // [4,2,256,448]
    const float* mask = (const float*)d_in[2];  // [4,1,256,448]
    float*    out  = (float*)d_out;
    float*    wacc = (float*)d_ws;                          // [B,HW] outlier weights
    unsigned* flag = (unsigned*)((float*)d_ws + BB * HW);   // outlier flag

    // zero wacc + flag every call (deterministic under graph replay)
    hipMemsetAsync(d_ws, 0, (size_t)(BB * HW + 4) * sizeof(float), stream);

    const int npix = BB * HW;
    flag_kernel<<<(npix + TPB - 1) / TPB, TPB, 0, stream>>>(flow, flag);
    cond_zero_kernel<<<2048, TPB, 0, stream>>>((float4*)out, flag);
    outlier_kernel<<<(npix + TPB - 1) / TPB, TPB, 0, stream>>>(inp, flow, mask, out, wacc, flag);
    gather_kernel<<<dim3(WW / TX, HH / TY, BB * NGRP), TPB, 0, stream>>>(inp, flow, mask, out, wacc, flag);
}

// Round 4
// 692.400 us; speedup vs baseline: 3.8073x; 1.0008x over previous
//
#include <hip/hip_runtime.h>

// Problem constants: B=4, C=64, H=256, W=448, fp32.
#define BB 4
#define CC 64
#define HH 256
#define WW 448
constexpr int HW  = HH * WW;    // 114688
constexpr int CHW = CC * HW;    // 7340032

// Gather-tile geometry
#define TX 32                   // tile width  (W=448 -> 14 tiles)
#define TY 16                   // tile height (H=256 -> 16 tiles)
#define TH 7                    // source window halo; "local" iff |d| <= 6
#define LOCAL_MAX 6.0f
#define WINX (TX + 2*TH)        // 46
#define WINY (TY + 2*TH)        // 30
#define NSRC (WINX * WINY)      // 1380
#define MAXS 6                  // ceil(NSRC / 256)
#define NCH 8                   // channels per block (chunk-group)
#define NGRP (CC / NCH)         // 8 chunk-groups
#define TPB 256
#define TXTY (TX * TY)          // 512

// HW fp32 LDS atomic add: ds_add_f32 (no return, no CAS loop).
// Generic->LDS pointer truncation yields the LDS byte offset (aperture is
// 2^32-aligned); __syncthreads drains lgkmcnt(0) before the barrier, so the
// accumulated values are visible to the normalize phase.
__device__ __forceinline__ void lds_fadd(float* p, float v) {
    asm volatile("ds_add_f32 %0, %1"
                 :: "v"((unsigned)(uintptr_t)p), "v"(v) : "memory");
}

// ws layout (floats): [0, B*HW) = weight accumulator (outliers only);
//                     [B*HW]    = outlier flag (as u32)

// ---------------------------------------------------------------------------
// K1: detect any source pixel with |flow| > LOCAL_MAX (rare path trigger).
// ---------------------------------------------------------------------------
__global__ __launch_bounds__(TPB) void flag_kernel(
    const float* __restrict__ flow, unsigned* __restrict__ flag)
{
    int p = blockIdx.x * TPB + threadIdx.x;
    if (p >= BB * HW) return;
    int b = p / HW, rem = p - b * HW;
    float dx = flow[(b * 2 + 0) * HW + rem];
    float dy = flow[(b * 2 + 1) * HW + rem];
    if (!((fabsf(dx) <= LOCAL_MAX) && (fabsf(dy) <= LOCAL_MAX)))
        atomicOr(flag, 1u);
}

// ---------------------------------------------------------------------------
// K2: zero d_out only if outliers exist (they atomically accumulate into it).
// ---------------------------------------------------------------------------
__global__ __launch_bounds__(TPB) void cond_zero_kernel(
    float4* __restrict__ out4, const unsigned* __restrict__ flag)
{
    if (*flag == 0u) return;
    const int n4 = BB * CHW / 4;
    for (int i = blockIdx.x * TPB + threadIdx.x; i < n4; i += gridDim.x * TPB)
        out4[i] = float4{0.f, 0.f, 0.f, 0.f};
}

// ---------------------------------------------------------------------------
// K3: rare-path scatter for outlier sources (global atomics, ~0 pixels usually).
// ---------------------------------------------------------------------------
__global__ __launch_bounds__(TPB) void outlier_kernel(
    const float* __restrict__ inp, const float* __restrict__ flow,
    const float* __restrict__ mask, float* __restrict__ acc,
    float* __restrict__ wacc, const unsigned* __restrict__ flag)
{
    if (*flag == 0u) return;
    int p = blockIdx.x * TPB + threadIdx.x;
    if (p >= BB * HW) return;
    int b = p / HW, rem = p - b * HW;
    int y = rem / WW, x = rem - y * WW;

    float dx = flow[(b * 2 + 0) * HW + rem];
    float dy = flow[(b * 2 + 1) * HW + rem];
    if ((fabsf(dx) <= LOCAL_MAX) && (fabsf(dy) <= LOCAL_MAX)) return; // local: gather handles

    float tx = (float)x + dx, ty = (float)y + dy;
    float x0f = floorf(tx), y0f = floorf(ty);
    int   x0 = (int)x0f, y0 = (int)y0f;
    float fx = tx - x0f, fy = ty - y0f;
    float wx[2] = {1.0f - fx, fx};
    float wy[2] = {1.0f - fy, fy};
    float m = expf(mask[b * HW + rem]);

    int   cidx[4];
    float cw[4];
    bool  cv[4];
#pragma unroll
    for (int j = 0; j < 4; ++j) {
        int xi = x0 + (j & 1), yi = y0 + (j >> 1);
        cv[j]   = (xi >= 0) & (xi < WW) & (yi >= 0) & (yi < HH);
        cidx[j] = yi * WW + xi;
        cw[j]   = wx[j & 1] * wy[j >> 1] * m;
    }
    float* wbase = wacc + b * HW;
#pragma unroll
    for (int j = 0; j < 4; ++j)
        if (cv[j]) unsafeAtomicAdd(wbase + cidx[j], cw[j]);
    const float* ibase = inp + b * CHW + rem;
    float*       obase = acc + b * CHW;
    for (int c = 0; c < CC; ++c) {
        float v = ibase[c * HW];
#pragma unroll
        for (int j = 0; j < 4; ++j)
            if (cv[j]) unsafeAtomicAdd(obase + c * HW + cidx[j], cw[j] * v);
    }
}

// ---------------------------------------------------------------------------
// K4: main gather-splat. Block owns an exclusive TXxTY output tile AND an
// 8-channel group. Single merged pass over the source window accumulates the
// weight plane + 8 value planes in LDS (HW ds_add_f32); then normalize +
// coalesced stores. 18 KB LDS -> 8 blocks/CU.
// ---------------------------------------------------------------------------
__global__ __launch_bounds__(TPB, 8) void gather_kernel(
    const float* __restrict__ inp, const float* __restrict__ flow,
    const float* __restrict__ mask, float* __restrict__ out,
    const float* __restrict__ wacc, const unsigned* __restrict__ flag)
{
    __shared__ float lds[(1 + NCH) * TXTY];   // [0,TXTY) = weights, then NCH planes
    float* wlds = lds;

    const int b    = blockIdx.z >> 3;         // batch
    const int grp  = blockIdx.z & 7;          // channel group
    const int bx0  = blockIdx.x * TX;
    const int by0  = blockIdx.y * TY;
    const int tid  = threadIdx.x;

    // zero all LDS planes
    {
        float4* z = (float4*)lds;
        constexpr int n4 = (1 + NCH) * TXTY / 4;   // 1152
#pragma unroll
        for (int i = 0; i < (n4 + TPB - 1) / TPB; ++i) {
            int idx = tid + i * TPB;
            if (idx < n4) z[idx] = float4{0.f, 0.f, 0.f, 0.f};
        }
    }
    __syncthreads();

    const float* __restrict__ fxp = flow + (b * 2 + 0) * HW;
    const float* __restrict__ fyp = flow + (b * 2 + 1) * HW;
    const float* __restrict__ mp  = mask + b * HW;
    const float* __restrict__ ib  = inp + (b * CC + grp * NCH) * HW;

    // --- merged accumulation pass over the source window
#pragma unroll 2
    for (int k = 0; k < MAXS; ++k) {
        const int s  = tid + k * TPB;
        const int sy = s / WINX;
        const int sx = s - sy * WINX;
        const int gx = bx0 - TH + sx;
        const int gy = by0 - TH + sy;
        bool v = (s < NSRC) & (gx >= 0) & (gx < WW) & (gy >= 0) & (gy < HH);
        if (!v) continue;
        const int sp = gy * WW + gx;

        const float dx = fxp[sp];
        const float dy = fyp[sp];
        if (!((fabsf(dx) <= LOCAL_MAX) && (fabsf(dy) <= LOCAL_MAX))) continue;

        const float tx  = (float)gx + dx;
        const float ty  = (float)gy + dy;
        const float x0f = floorf(tx), y0f = floorf(ty);
        const int   lx  = (int)x0f - bx0;
        const int   ly  = (int)y0f - by0;
        // 2x2 corner box vs tile: skip if no overlap at all
        if (lx < -1 || lx >= TX || ly < -1 || ly >= TY) continue;

        const float fx = tx - x0f, fy = ty - y0f;
        const float ox = 1.0f - fx, oy = 1.0f - fy;
        const float m  = expf(mp[sp]);
        float w4[4] = {ox * oy * m, fx * oy * m, ox * fy * m, fx * fy * m};

        // weight plane
#pragma unroll
        for (int j = 0; j < 4; ++j) {
            const int cx = lx + (j & 1), cy = ly + (j >> 1);
            if (cx >= 0 && cx < TX && cy >= 0 && cy < TY)
                lds_fadd(&wlds[cy * TX + cx], w4[j]);
        }
        // value planes (8 channels)
        float vv[NCH];
#pragma unroll
        for (int c = 0; c < NCH; ++c) vv[c] = ib[c * HW + sp];
#pragma unroll
        for (int j = 0; j < 4; ++j) {
            const int cx = lx + (j & 1), cy = ly + (j >> 1);
            if (cx >= 0 && cx < TX && cy >= 0 && cy < TY) {
                const float wj = w4[j];
                float* vp = &lds[TXTY + cy * TX + cx];
#pragma unroll
                for (int c = 0; c < NCH; ++c)
                    lds_fadd(vp + c * TXTY, wj * vv[c]);
            }
        }
    }
    __syncthreads();

    // --- normalize + store (2 pixels per thread x 8 channels)
    const bool has_out = (*flag != 0u);
    const int  obase   = (b * CC + grp * NCH) * HW;
#pragma unroll
    for (int t = 0; t < 2; ++t) {
        const int p  = tid + t * TPB;
        const int py = p >> 5, px = p & 31;           // TX = 32
        const int gpix = (by0 + py) * WW + (bx0 + px);
        const float rden = 1.0f / (wlds[p] + wacc[b * HW + gpix] + 1e-7f);
#pragma unroll
        for (int c = 0; c < NCH; ++c) {
            float a = lds[TXTY + c * TXTY + p];
            const int gi = obase + c * HW + gpix;
            if (has_out) a += out[gi];                 // rare outlier contributions
            out[gi] = a * rden;
        }
    }
}

extern "C" void kernel_launch(void* const* d_in, const int* in_sizes, int n_in,
                              void* d_out, int out_size, void* d_ws, size_t ws_size,
                              hipStream_t stream) {
    const float* inp  = (const float*)d_in[0];  // [4,64,256,448]
    const float* flow = (const float*)d_in[1];  // [4,2,256,448]
    const float* mask = (const float*)d_in[2];  // [4,1,256,448]
    float*    out  = (float*)d_out;
    float*    wacc = (float*)d_ws;                          // [B,HW] outlier weights
    unsigned* flag = (unsigned*)((float*)d_ws + BB * HW);   // outlier flag

    // zero wacc + flag every call (deterministic under graph replay)
    hipMemsetAsync(d_ws, 0, (size_t)(BB * HW + 4) * sizeof(float), stream);

    const int npix = BB * HW;
    flag_kernel<<<(npix + TPB - 1) / TPB, TPB, 0, stream>>>(flow, flag);
    cond_zero_kernel<<<2048, TPB, 0, stream>>>((float4*)out, flag);
    outlier_kernel<<<(npix + TPB - 1) / TPB, TPB, 0, stream>>>(inp, flow, mask, out, wacc, flag);
    gather_kernel<<<dim3(WW / TX, HH / TY, BB * NGRP), TPB, 0, stream>>>(inp, flow, mask, out, wacc, flag);
}